// Round 3
// baseline (1243.098 us; speedup 1.0000x reference)
//
#include <hip/hip_runtime.h>

#define N_NODES 100000
#define N_EDGES 1600000
#define N_FEAT 7
#define HID 128
#define N_CLASS 5
#define N_GRAPHS 8
#define NPB 16   // nodes per block in fused hidden-layer kernel
#define SCAN_NBLK ((N_NODES + 1023) / 1024)   // 98

// ---------------- CSR build (dst-sorted adjacency) ----------------

__global__ void hist_kernel(const int* __restrict__ dst, int* __restrict__ deg) {
    int e = blockIdx.x * blockDim.x + threadIdx.x;
    if (e < N_EDGES) atomicAdd(&deg[dst[e]], 1);
}

// phase 1: per-block exclusive scan of 1024 deg values; block total -> bsum
__global__ __launch_bounds__(1024) void scan_phase1(const int* __restrict__ deg,
                                                    int* __restrict__ tmp,
                                                    int* __restrict__ bsum) {
    __shared__ int s[1024];
    int tid = threadIdx.x;
    int i = blockIdx.x * 1024 + tid;
    int v = (i < N_NODES) ? deg[i] : 0;
    s[tid] = v;
    __syncthreads();
    for (int off = 1; off < 1024; off <<= 1) {
        int u = (tid >= off) ? s[tid - off] : 0;
        __syncthreads();
        s[tid] += u;
        __syncthreads();
    }
    if (i < N_NODES) tmp[i] = s[tid] - v;            // exclusive
    if (tid == 1023) bsum[blockIdx.x] = s[1023];
}

// phase 2: single 128-thread block scans the 98 block sums (exclusive, in-place)
__global__ __launch_bounds__(128) void scan_phase2(int* __restrict__ bsum) {
    __shared__ int s[128];
    int tid = threadIdx.x;
    int v = (tid < SCAN_NBLK) ? bsum[tid] : 0;
    s[tid] = v;
    __syncthreads();
    for (int off = 1; off < 128; off <<= 1) {
        int u = (tid >= off) ? s[tid - off] : 0;
        __syncthreads();
        s[tid] += u;
        __syncthreads();
    }
    if (tid < SCAN_NBLK) bsum[tid] = s[tid] - v;
}

// phase 3: rowptr[i] = tmp[i] + bsum[blk]; cursor copy; sentinel
__global__ __launch_bounds__(1024) void scan_phase3(const int* __restrict__ tmp,
                                                    const int* __restrict__ bsum,
                                                    int* __restrict__ rowptr,
                                                    int* __restrict__ cursor) {
    int i = blockIdx.x * 1024 + threadIdx.x;
    if (i < N_NODES) {
        int r = tmp[i] + bsum[blockIdx.x];
        rowptr[i] = r;
        cursor[i] = r;
    }
    if (i == 0) rowptr[N_NODES] = N_EDGES;
}

// pack (src, edge_attr) into one 8B record at its CSR slot
__global__ void scatter_kernel(const int* __restrict__ src, const int* __restrict__ dst,
                               const float* __restrict__ ea, int* __restrict__ cursor,
                               int2* __restrict__ csr) {
    int e = blockIdx.x * blockDim.x + threadIdx.x;
    if (e >= N_EDGES) return;
    int d = dst[e];
    int p = atomicAdd(&cursor[d], 1);
    csr[p] = make_int2(src[e], __float_as_int(ea[e]));
}

// ---------------- Layer 1 (in=7) ----------------

// one wave per node: strided gather over incoming edges, butterfly reduce
__global__ __launch_bounds__(64) void agg_l1(const float* __restrict__ x,
                                             const int2* __restrict__ csr,
                                             const int* __restrict__ rowptr,
                                             const float* __restrict__ We,
                                             const float* __restrict__ be,
                                             float* __restrict__ agg) {
    int n = blockIdx.x;
    int lane = threadIdx.x;
    int r0 = rowptr[n], r1 = rowptr[n + 1];
    float we[N_FEAT], bee[N_FEAT], p[N_FEAT];
#pragma unroll
    for (int k = 0; k < N_FEAT; ++k) { we[k] = We[k]; bee[k] = be[k]; p[k] = 0.f; }
    for (int i = r0 + lane; i < r1; i += 64) {
        int2 sa = csr[i];
        int s = sa.x;
        float a = __int_as_float(sa.y);
#pragma unroll
        for (int k = 0; k < N_FEAT; ++k) {
            float m = x[s * N_FEAT + k] + a * we[k] + bee[k];
            p[k] += m > 0.f ? m : 0.f;
        }
    }
#pragma unroll
    for (int off = 32; off >= 1; off >>= 1)
#pragma unroll
        for (int k = 0; k < N_FEAT; ++k)
            p[k] += __shfl_xor(p[k], off, 64);
    if (lane == 0) {
#pragma unroll
        for (int k = 0; k < N_FEAT; ++k) agg[n * N_FEAT + k] = p[k];
    }
}

__global__ void node_l1(const float* __restrict__ x, const float* __restrict__ agg,
                        const float* __restrict__ W, const float* __restrict__ b,
                        float* __restrict__ h) {
    __shared__ float t[N_FEAT];
    int n = blockIdx.x;
    int j = threadIdx.x;
    if (j < N_FEAT) t[j] = agg[n * N_FEAT + j] + x[n * N_FEAT + j];
    __syncthreads();
    float acc = b[j];
#pragma unroll
    for (int k = 0; k < N_FEAT; ++k) acc += t[k] * W[k * HID + j];
    h[n * HID + j] = acc > 0.f ? acc : 0.f;
}

// ---------------- Fused hidden layer: gather-aggregate + GEMV ----------------
// block = 128 threads (j = feature), owns NPB consecutive nodes.
// hout MUST differ from hin (other blocks gather hin rows concurrently).
__global__ __launch_bounds__(128) void hidden_layer(
        const float* __restrict__ hin, const int2* __restrict__ csr,
        const int* __restrict__ rowptr, const float* __restrict__ We,
        const float* __restrict__ be, const float* __restrict__ W,
        const float* __restrict__ b, float* __restrict__ hout) {
    __shared__ float t[NPB][HID];
    __shared__ int2 ebuf[128];
    int j = threadIdx.x;
    int n0 = blockIdx.x * NPB;
    float wej = We[j], bej = be[j];

    for (int m = 0; m < NPB; ++m) {
        int n = n0 + m;
        int r0 = rowptr[n], r1 = rowptr[n + 1];
        float acc = 0.f;
        for (int c = r0; c < r1; c += 128) {
            int cnt = r1 - c; if (cnt > 128) cnt = 128;
            __syncthreads();                 // protect ebuf reuse
            if (j < cnt) ebuf[j] = csr[c + j];
            __syncthreads();
            for (int i = 0; i < cnt; ++i) {
                int s = ebuf[i].x;
                float a = __int_as_float(ebuf[i].y);
                float mm = hin[(size_t)s * HID + j] + a * wej + bej;
                acc += mm > 0.f ? mm : 0.f;
            }
        }
        t[m][j] = acc + hin[(size_t)n * HID + j];
    }
    __syncthreads();

    float out[NPB];
#pragma unroll
    for (int m = 0; m < NPB; ++m) out[m] = b[j];
    for (int k = 0; k < HID; ++k) {
        float w = W[k * HID + j];
#pragma unroll
        for (int m = 0; m < NPB; ++m) out[m] += t[m][k] * w;
    }
#pragma unroll
    for (int m = 0; m < NPB; ++m) {
        float v = out[m];
        hout[(size_t)(n0 + m) * HID + j] = v > 0.f ? v : 0.f;
    }
}

// ---------------- Pooling + head ----------------

__global__ void pool_kernel(const float* __restrict__ h, const int* __restrict__ batch,
                            float* __restrict__ pool, float* __restrict__ cnt) {
    int n0 = blockIdx.x * 64;
    int j = threadIdx.x;
    int nend = n0 + 64;
    if (nend > N_NODES) nend = N_NODES;
    if (n0 >= N_NODES) return;
    float sum = 0.f;
    int curg = batch[n0];
    int runstart = n0;
    for (int n = n0; n < nend; ++n) {
        int g = batch[n];
        if (g != curg) {
            atomicAdd(&pool[curg * HID + j], sum);
            if (j == 0) atomicAdd(&cnt[curg], (float)(n - runstart));
            sum = 0.f;
            curg = g;
            runstart = n;
        }
        sum += h[(size_t)n * HID + j];
    }
    atomicAdd(&pool[curg * HID + j], sum);
    if (j == 0) atomicAdd(&cnt[curg], (float)(nend - runstart));
}

__global__ void final_kernel(const float* __restrict__ pool, const float* __restrict__ cnt,
                             const float* __restrict__ Wlin, const float* __restrict__ blin,
                             float* __restrict__ out) {
    int idx = threadIdx.x;
    if (idx >= N_GRAPHS * N_CLASS) return;
    int g = idx / N_CLASS, c = idx % N_CLASS;
    float invc = 1.f / fmaxf(cnt[g], 1.f);
    float acc = blin[c];
    for (int j = 0; j < HID; ++j) acc += pool[g * HID + j] * invc * Wlin[j * N_CLASS + c];
    out[idx] = acc;
}

extern "C" void kernel_launch(void* const* d_in, const int* in_sizes, int n_in,
                              void* d_out, int out_size, void* d_ws, size_t ws_size,
                              hipStream_t stream) {
    const float* x    = (const float*)d_in[0];
    const int*   ei   = (const int*)d_in[1];
    const float* ea   = (const float*)d_in[2];
    const int*   batch= (const int*)d_in[3];
    const float* We1  = (const float*)d_in[4];
    const float* be1  = (const float*)d_in[5];
    const float* W1   = (const float*)d_in[6];
    const float* b1   = (const float*)d_in[7];
    const float* We2  = (const float*)d_in[8];
    const float* be2  = (const float*)d_in[9];
    const float* W2   = (const float*)d_in[10];
    const float* b2   = (const float*)d_in[11];
    const float* We3  = (const float*)d_in[12];
    const float* be3  = (const float*)d_in[13];
    const float* W3   = (const float*)d_in[14];
    const float* b3   = (const float*)d_in[15];
    const float* Wlin = (const float*)d_in[16];
    const float* blin = (const float*)d_in[17];

    const int* src = ei;
    const int* dst = ei + N_EDGES;

    // workspace layout (csr first: 8B-aligned at base)
    char* w = (char*)d_ws;
    int2*  csr    = (int2*)w;                    w += sizeof(int2) * (size_t)N_EDGES;
    float* A      = (float*)w;                   w += sizeof(float) * (size_t)N_NODES * HID;
    float* B      = (float*)w;                   w += sizeof(float) * (size_t)N_NODES * HID;
    float* agg1   = (float*)w;                   w += sizeof(float) * (size_t)N_NODES * N_FEAT;
    float* pool   = (float*)w;                   w += sizeof(float) * N_GRAPHS * HID;
    float* cnt    = (float*)w;                   w += sizeof(float) * N_GRAPHS;
    int*   rowptr = (int*)w;                     w += sizeof(int) * (N_NODES + 1);
    int*   cursor = (int*)w;                     w += sizeof(int) * N_NODES;
    int*   deg    = (int*)w;                     w += sizeof(int) * N_NODES;
    int*   stmp   = (int*)w;                     w += sizeof(int) * N_NODES;
    int*   bsum   = (int*)w;                     w += sizeof(int) * SCAN_NBLK;

    // ---- CSR build ----
    hipMemsetAsync(deg, 0, sizeof(int) * N_NODES, stream);
    hipMemsetAsync(pool, 0, sizeof(float) * (N_GRAPHS * HID + N_GRAPHS), stream);
    hist_kernel<<<(N_EDGES + 255) / 256, 256, 0, stream>>>(dst, deg);
    scan_phase1<<<SCAN_NBLK, 1024, 0, stream>>>(deg, stmp, bsum);
    scan_phase2<<<1, 128, 0, stream>>>(bsum);
    scan_phase3<<<SCAN_NBLK, 1024, 0, stream>>>(stmp, bsum, rowptr, cursor);
    scatter_kernel<<<(N_EDGES + 255) / 256, 256, 0, stream>>>(src, dst, ea, cursor, csr);

    // ---- Layer 1 ----
    agg_l1<<<N_NODES, 64, 0, stream>>>(x, csr, rowptr, We1, be1, agg1);
    node_l1<<<N_NODES, HID, 0, stream>>>(x, agg1, W1, b1, A);            // A = h1

    // ---- Layer 2: A -> B ----
    hidden_layer<<<N_NODES / NPB, 128, 0, stream>>>(A, csr, rowptr, We2, be2, W2, b2, B);

    // ---- Layer 3: B -> A ----
    hidden_layer<<<N_NODES / NPB, 128, 0, stream>>>(B, csr, rowptr, We3, be3, W3, b3, A);

    // ---- Pool + head ----
    pool_kernel<<<(N_NODES + 63) / 64, HID, 0, stream>>>(A, batch, pool, cnt);
    final_kernel<<<1, 64, 0, stream>>>(pool, cnt, Wlin, blin, (float*)d_out);
}

// Round 4
// 677.151 us; speedup vs baseline: 1.8358x; 1.8358x over previous
//
#include <hip/hip_runtime.h>
#include <hip/hip_bf16.h>

#define N_NODES 100000
#define N_EDGES 1600000
#define N_FEAT 7
#define HID 128
#define N_CLASS 5
#define N_GRAPHS 8
#define NPB 8   // nodes per block in fused hidden-layer kernel
#define SCAN_NBLK ((N_NODES + 1023) / 1024)   // 98

typedef __hip_bfloat16 bf16;

// ---------------- CSR build (dst-sorted adjacency) ----------------

__global__ void hist_kernel(const int* __restrict__ dst, int* __restrict__ deg) {
    int e = blockIdx.x * blockDim.x + threadIdx.x;
    if (e < N_EDGES) atomicAdd(&deg[dst[e]], 1);
}

__global__ __launch_bounds__(1024) void scan_phase1(const int* __restrict__ deg,
                                                    int* __restrict__ tmp,
                                                    int* __restrict__ bsum) {
    __shared__ int s[1024];
    int tid = threadIdx.x;
    int i = blockIdx.x * 1024 + tid;
    int v = (i < N_NODES) ? deg[i] : 0;
    s[tid] = v;
    __syncthreads();
    for (int off = 1; off < 1024; off <<= 1) {
        int u = (tid >= off) ? s[tid - off] : 0;
        __syncthreads();
        s[tid] += u;
        __syncthreads();
    }
    if (i < N_NODES) tmp[i] = s[tid] - v;            // exclusive
    if (tid == 1023) bsum[blockIdx.x] = s[1023];
}

__global__ __launch_bounds__(128) void scan_phase2(int* __restrict__ bsum) {
    __shared__ int s[128];
    int tid = threadIdx.x;
    int v = (tid < SCAN_NBLK) ? bsum[tid] : 0;
    s[tid] = v;
    __syncthreads();
    for (int off = 1; off < 128; off <<= 1) {
        int u = (tid >= off) ? s[tid - off] : 0;
        __syncthreads();
        s[tid] += u;
        __syncthreads();
    }
    if (tid < SCAN_NBLK) bsum[tid] = s[tid] - v;
}

__global__ __launch_bounds__(1024) void scan_phase3(const int* __restrict__ tmp,
                                                    const int* __restrict__ bsum,
                                                    int* __restrict__ rowptr,
                                                    int* __restrict__ cursor) {
    int i = blockIdx.x * 1024 + threadIdx.x;
    if (i < N_NODES) {
        int r = tmp[i] + bsum[blockIdx.x];
        rowptr[i] = r;
        cursor[i] = r;
    }
    if (i == 0) rowptr[N_NODES] = N_EDGES;
}

__global__ void scatter_kernel(const int* __restrict__ src, const int* __restrict__ dst,
                               const float* __restrict__ ea, int* __restrict__ cursor,
                               int2* __restrict__ csr) {
    int e = blockIdx.x * blockDim.x + threadIdx.x;
    if (e >= N_EDGES) return;
    int d = dst[e];
    int p = atomicAdd(&cursor[d], 1);
    csr[p] = make_int2(src[e], __float_as_int(ea[e]));
}

// ---------------- Layer 1 (in=7) ----------------

__global__ __launch_bounds__(64) void agg_l1(const float* __restrict__ x,
                                             const int2* __restrict__ csr,
                                             const int* __restrict__ rowptr,
                                             const float* __restrict__ We,
                                             const float* __restrict__ be,
                                             float* __restrict__ agg) {
    int n = blockIdx.x;
    int lane = threadIdx.x;
    int r0 = rowptr[n], r1 = rowptr[n + 1];
    float we[N_FEAT], bee[N_FEAT], p[N_FEAT];
#pragma unroll
    for (int k = 0; k < N_FEAT; ++k) { we[k] = We[k]; bee[k] = be[k]; p[k] = 0.f; }
    for (int i = r0 + lane; i < r1; i += 64) {
        int2 sa = csr[i];
        int s = sa.x;
        float a = __int_as_float(sa.y);
#pragma unroll
        for (int k = 0; k < N_FEAT; ++k) {
            float m = x[s * N_FEAT + k] + a * we[k] + bee[k];
            p[k] += m > 0.f ? m : 0.f;
        }
    }
#pragma unroll
    for (int off = 32; off >= 1; off >>= 1)
#pragma unroll
        for (int k = 0; k < N_FEAT; ++k)
            p[k] += __shfl_xor(p[k], off, 64);
    if (lane == 0) {
#pragma unroll
        for (int k = 0; k < N_FEAT; ++k) agg[n * N_FEAT + k] = p[k];
    }
}

__global__ void node_l1(const float* __restrict__ x, const float* __restrict__ agg,
                        const float* __restrict__ W, const float* __restrict__ b,
                        bf16* __restrict__ h) {
    __shared__ float t[N_FEAT];
    int n = blockIdx.x;
    int j = threadIdx.x;
    if (j < N_FEAT) t[j] = agg[n * N_FEAT + j] + x[n * N_FEAT + j];
    __syncthreads();
    float acc = b[j];
#pragma unroll
    for (int k = 0; k < N_FEAT; ++k) acc += t[k] * W[k * HID + j];
    h[n * HID + j] = __float2bfloat16(acc > 0.f ? acc : 0.f);
}

// ---------------- Fused hidden layer: gather-aggregate + GEMV ----------------
// block = 128 threads (j = feature), owns NPB consecutive nodes.
// Edge records read via wave-uniform addresses (scalar loads, no LDS staging).
// hout MUST differ from hin (other blocks gather hin rows concurrently).
__global__ __launch_bounds__(128) void hidden_layer(
        const bf16* __restrict__ hin, const int2* __restrict__ csr,
        const int* __restrict__ rowptr, const float* __restrict__ We,
        const float* __restrict__ be, const float* __restrict__ W,
        const float* __restrict__ b, bf16* __restrict__ hout) {
    __shared__ float t[NPB][HID];
    int j = threadIdx.x;
    int n0 = blockIdx.x * NPB;
    float wej = We[j], bej = be[j];

    for (int m = 0; m < NPB; ++m) {
        int n = n0 + m;
        int r0 = rowptr[n], r1 = rowptr[n + 1];
        float acc = 0.f;
#pragma unroll 4
        for (int i = r0; i < r1; ++i) {
            int2 sa = csr[i];               // uniform across block -> scalar load
            int s = sa.x;
            float a = __int_as_float(sa.y);
            float mm = __bfloat162float(hin[(size_t)s * HID + j]) + a * wej + bej;
            acc += mm > 0.f ? mm : 0.f;
        }
        t[m][j] = acc + __bfloat162float(hin[(size_t)n * HID + j]);
    }
    __syncthreads();

    float out[NPB];
#pragma unroll
    for (int m = 0; m < NPB; ++m) out[m] = b[j];
    for (int k = 0; k < HID; ++k) {
        float w = W[k * HID + j];
#pragma unroll
        for (int m = 0; m < NPB; ++m) out[m] += t[m][k] * w;
    }
#pragma unroll
    for (int m = 0; m < NPB; ++m) {
        float v = out[m];
        hout[(size_t)(n0 + m) * HID + j] = __float2bfloat16(v > 0.f ? v : 0.f);
    }
}

// ---------------- Pooling + head ----------------

__global__ void pool_kernel(const bf16* __restrict__ h, const int* __restrict__ batch,
                            float* __restrict__ pool, float* __restrict__ cnt) {
    int n0 = blockIdx.x * 64;
    int j = threadIdx.x;
    int nend = n0 + 64;
    if (nend > N_NODES) nend = N_NODES;
    if (n0 >= N_NODES) return;
    float sum = 0.f;
    int curg = batch[n0];
    int runstart = n0;
    for (int n = n0; n < nend; ++n) {
        int g = batch[n];
        if (g != curg) {
            atomicAdd(&pool[curg * HID + j], sum);
            if (j == 0) atomicAdd(&cnt[curg], (float)(n - runstart));
            sum = 0.f;
            curg = g;
            runstart = n;
        }
        sum += __bfloat162float(h[(size_t)n * HID + j]);
    }
    atomicAdd(&pool[curg * HID + j], sum);
    if (j == 0) atomicAdd(&cnt[curg], (float)(nend - runstart));
}

__global__ void final_kernel(const float* __restrict__ pool, const float* __restrict__ cnt,
                             const float* __restrict__ Wlin, const float* __restrict__ blin,
                             float* __restrict__ out) {
    int idx = threadIdx.x;
    if (idx >= N_GRAPHS * N_CLASS) return;
    int g = idx / N_CLASS, c = idx % N_CLASS;
    float invc = 1.f / fmaxf(cnt[g], 1.f);
    float acc = blin[c];
    for (int j = 0; j < HID; ++j) acc += pool[g * HID + j] * invc * Wlin[j * N_CLASS + c];
    out[idx] = acc;
}

extern "C" void kernel_launch(void* const* d_in, const int* in_sizes, int n_in,
                              void* d_out, int out_size, void* d_ws, size_t ws_size,
                              hipStream_t stream) {
    const float* x    = (const float*)d_in[0];
    const int*   ei   = (const int*)d_in[1];
    const float* ea   = (const float*)d_in[2];
    const int*   batch= (const int*)d_in[3];
    const float* We1  = (const float*)d_in[4];
    const float* be1  = (const float*)d_in[5];
    const float* W1   = (const float*)d_in[6];
    const float* b1   = (const float*)d_in[7];
    const float* We2  = (const float*)d_in[8];
    const float* be2  = (const float*)d_in[9];
    const float* W2   = (const float*)d_in[10];
    const float* b2   = (const float*)d_in[11];
    const float* We3  = (const float*)d_in[12];
    const float* be3  = (const float*)d_in[13];
    const float* W3   = (const float*)d_in[14];
    const float* b3   = (const float*)d_in[15];
    const float* Wlin = (const float*)d_in[16];
    const float* blin = (const float*)d_in[17];

    const int* src = ei;
    const int* dst = ei + N_EDGES;

    // workspace layout (csr first: 8B-aligned at base)
    char* w = (char*)d_ws;
    int2*  csr    = (int2*)w;                    w += sizeof(int2) * (size_t)N_EDGES;
    bf16*  A      = (bf16*)w;                    w += sizeof(bf16) * (size_t)N_NODES * HID;
    bf16*  B      = (bf16*)w;                    w += sizeof(bf16) * (size_t)N_NODES * HID;
    float* agg1   = (float*)w;                   w += sizeof(float) * (size_t)N_NODES * N_FEAT;
    float* pool   = (float*)w;                   w += sizeof(float) * N_GRAPHS * HID;
    float* cnt    = (float*)w;                   w += sizeof(float) * N_GRAPHS;
    int*   rowptr = (int*)w;                     w += sizeof(int) * (N_NODES + 1);
    int*   cursor = (int*)w;                     w += sizeof(int) * N_NODES;
    int*   deg    = (int*)w;                     w += sizeof(int) * N_NODES;
    int*   stmp   = (int*)w;                     w += sizeof(int) * N_NODES;
    int*   bsum   = (int*)w;                     w += sizeof(int) * SCAN_NBLK;

    // ---- CSR build ----
    hipMemsetAsync(deg, 0, sizeof(int) * N_NODES, stream);
    hipMemsetAsync(pool, 0, sizeof(float) * (N_GRAPHS * HID + N_GRAPHS), stream);
    hist_kernel<<<(N_EDGES + 255) / 256, 256, 0, stream>>>(dst, deg);
    scan_phase1<<<SCAN_NBLK, 1024, 0, stream>>>(deg, stmp, bsum);
    scan_phase2<<<1, 128, 0, stream>>>(bsum);
    scan_phase3<<<SCAN_NBLK, 1024, 0, stream>>>(stmp, bsum, rowptr, cursor);
    scatter_kernel<<<(N_EDGES + 255) / 256, 256, 0, stream>>>(src, dst, ea, cursor, csr);

    // ---- Layer 1 ----
    agg_l1<<<N_NODES, 64, 0, stream>>>(x, csr, rowptr, We1, be1, agg1);
    node_l1<<<N_NODES, HID, 0, stream>>>(x, agg1, W1, b1, A);            // A = h1 (bf16)

    // ---- Layer 2: A -> B ----
    hidden_layer<<<N_NODES / NPB, 128, 0, stream>>>(A, csr, rowptr, We2, be2, W2, b2, B);

    // ---- Layer 3: B -> A ----
    hidden_layer<<<N_NODES / NPB, 128, 0, stream>>>(B, csr, rowptr, We3, be3, W3, b3, A);

    // ---- Pool + head ----
    pool_kernel<<<(N_NODES + 63) / 64, HID, 0, stream>>>(A, batch, pool, cnt);
    final_kernel<<<1, 64, 0, stream>>>(pool, cnt, Wlin, blin, (float*)d_out);
}